// Round 1
// 318.496 us; speedup vs baseline: 1.0592x; 1.0592x over previous
//
#include <hip/hip_runtime.h>
#include <hip/hip_bf16.h>

#define B_ 32
#define C_ 384
#define N_ 4096
#define M_ 64
#define R_ 16

typedef __attribute__((ext_vector_type(8))) short short8;
typedef __attribute__((ext_vector_type(4))) float f32x4;
typedef __attribute__((ext_vector_type(4))) int i32x4;

static __device__ __forceinline__ unsigned short f2bf(float f) {
    union { float f; unsigned u; } v; v.f = f;
    unsigned r = v.u + 0x7fffu + ((v.u >> 16) & 1u);   // RNE
    return (unsigned short)(r >> 16);
}

// =====================================================================
// Kernel 0 (unchanged): W2 = U*Vw (bf16 [64][384]) and b2 = U*Vb -> d_ws.
// =====================================================================
__global__ __launch_bounds__(256) void k_w2(
    const float* __restrict__ Vw, const float* __restrict__ Vb,
    const float* __restrict__ U, unsigned short* __restrict__ W2,
    float* __restrict__ b2)
{
    __shared__ float vws[16 * 384];
    __shared__ float vbs[16];
    const int t = threadIdx.x;

    #pragma unroll
    for (int j = 0; j < 6; ++j)
        ((float4*)vws)[t + j * 256] = ((const float4*)Vw)[t + j * 256];
    if (t < 16) vbs[t] = Vb[t];
    __syncthreads();

    const int m  = blockIdx.x * 8 + (t >> 5);
    const int cg = t & 31;
    float u[R_];
    #pragma unroll
    for (int r = 0; r < R_; ++r) u[r] = U[m * R_ + r];
    if (cg == 0) {
        float a = 0.f;
        #pragma unroll
        for (int r = 0; r < R_; ++r) a = fmaf(u[r], vbs[r], a);
        b2[m] = a;
    }
    #pragma unroll
    for (int j = 0; j < 6; ++j) {
        const int c = cg * 2 + j * 64;
        float a0 = 0.f, a1 = 0.f;
        #pragma unroll
        for (int r = 0; r < R_; ++r) {
            float2 vv = *(const float2*)(vws + r * C_ + c);
            a0 = fmaf(u[r], vv.x, a0);
            a1 = fmaf(u[r], vv.y, a1);
        }
        unsigned pk = (unsigned)f2bf(a0) | ((unsigned)f2bf(a1) << 16);
        *(unsigned*)&W2[m * C_ + c] = pk;
    }
}

// =====================================================================
// Fused kernel: per (b, 512-n range): for each 128-n subtile:
//   stream x once -> LDS (two layouts) -> logits MFMA -> softmax (cross-wave)
//   -> write S (f32) + slds (bf16) -> pooling MFMA accum in regs.
// Epilogue: atomicAdd T. Grid 32*8 = 256 blocks, 512 thr (8 waves).
// LDS: xcn 96KB + union(xts 17KB, slds 16KB) + wred 4KB = 117 KB -> 1/CU.
// =====================================================================
__global__ __launch_bounds__(512, 2) void k_fused(
    const float* __restrict__ x, const unsigned short* __restrict__ W2,
    const float* __restrict__ b2g, float* __restrict__ S, float* __restrict__ T)
{
    __shared__ unsigned short xcn[C_ * 128];      // [c][n] bf16, XOR-swizzled rows
    __shared__ union {
        unsigned short xts[128][68];              // [n][c-chunk64] bf16 (+4 pad)
        unsigned short slds[M_ * 128];            // [m][n] bf16, XOR-swizzled
    } uu;
    __shared__ float wred[2][4][128];             // cross-wave softmax max/sum

    const int t    = threadIdx.x;
    const int lane = t & 63;
    const int col  = lane & 15;
    const int q    = lane >> 4;
    const int w    = t >> 6;
    const int g    = w >> 1;      // logits m-group (16 m each)
    const int h    = w & 1;       // logits n-half (64 n each)

    const int b  = blockIdx.x >> 3;
    const int nq = blockIdx.x & 7;

    // Per-wave W2 A-fragments in VGPRs (48 regs), loaded once (L2-hot).
    short8 af1[12];
    #pragma unroll
    for (int kk = 0; kk < 12; ++kk)
        af1[kk] = *(const short8*)(W2 + (g * 16 + col) * C_ + kk * 32 + q * 8);

    float bias[4];
    #pragma unroll
    for (int r = 0; r < 4; ++r) bias[r] = b2g[g * 16 + q * 4 + r];

    // Pooling accumulators: c = w*48 + ci*16 + (q*4+r), m = mt*16 + col.
    f32x4 acc2[3][4];
    #pragma unroll
    for (int ci = 0; ci < 3; ++ci)
        #pragma unroll
        for (int mt = 0; mt < 4; ++mt) acc2[ci][mt] = (f32x4){0.f, 0.f, 0.f, 0.f};

    const float* xb = x + (size_t)b * C_ * N_ + nq * 512 + 2 * lane;

    float2 xv[2][8];
    auto issue = [&](float2 (&dst)[8], int sub_, int kc_) {
        const float* xp = xb + (size_t)(kc_ * 64 + w * 8) * N_ + sub_ * 128;
        #pragma unroll
        for (int i = 0; i < 8; ++i)
            dst[i] = *(const float2*)(xp + (size_t)i * N_);
    };

    issue(xv[0], 0, 0);

    for (int sub = 0; sub < 4; ++sub) {
        f32x4 acc1[4];
        #pragma unroll
        for (int nt = 0; nt < 4; ++nt) acc1[nt] = (f32x4){0.f, 0.f, 0.f, 0.f};

        // ---- K-loop: 6 chunks of 64 c; load(kc+1) in flight over chunk kc ----
        #pragma unroll
        for (int kc = 0; kc < 6; ++kc) {
            if (kc < 5) issue(xv[(kc + 1) & 1], sub, kc + 1);
            {
                float2 (&v)[8] = xv[kc & 1];
                unsigned short bx[8], by[8];
                #pragma unroll
                for (int i = 0; i < 8; ++i) { bx[i] = f2bf(v[i].x); by[i] = f2bf(v[i].y); }
                // xcn[c][n]: all lanes same row -> conflict-free b32 writes
                #pragma unroll
                for (int i = 0; i < 8; ++i) {
                    int c = kc * 64 + w * 8 + i;
                    unsigned pk = (unsigned)bx[i] | ((unsigned)by[i] << 16);
                    *(unsigned*)((char*)xcn + c * 256 + ((lane * 4) ^ ((c & 7) << 4))) = pk;
                }
                // xts[n][c]: b128, rows 2*lane / 2*lane+1 (pad 68 -> conflict-free)
                i32x4 pa, pb;
                #pragma unroll
                for (int j = 0; j < 4; ++j) {
                    pa[j] = (int)((unsigned)bx[2 * j] | ((unsigned)bx[2 * j + 1] << 16));
                    pb[j] = (int)((unsigned)by[2 * j] | ((unsigned)by[2 * j + 1] << 16));
                }
                *(i32x4*)&uu.xts[2 * lane][w * 8]     = pa;
                *(i32x4*)&uu.xts[2 * lane + 1][w * 8] = pb;
            }
            __syncthreads();
            #pragma unroll
            for (int ks = 0; ks < 2; ++ks) {
                short8 bfr[4];
                #pragma unroll
                for (int nt = 0; nt < 4; ++nt)
                    bfr[nt] = *(const short8*)&uu.xts[h * 64 + nt * 16 + col][ks * 32 + q * 8];
                #pragma unroll
                for (int nt = 0; nt < 4; ++nt)
                    acc1[nt] = __builtin_amdgcn_mfma_f32_16x16x32_bf16(
                        af1[kc * 2 + ks], bfr[nt], acc1[nt], 0, 0, 0);
            }
            __syncthreads();
        }

        // ---- softmax over m = 64 (4 m-group waves exchange via LDS) ----
        #pragma unroll
        for (int nt = 0; nt < 4; ++nt) {
            float mx = -3.4e38f;
            #pragma unroll
            for (int r = 0; r < 4; ++r) {
                float vv = acc1[nt][r] + bias[r];
                acc1[nt][r] = vv;
                mx = fmaxf(mx, vv);
            }
            mx = fmaxf(mx, __shfl_xor(mx, 16, 64));
            mx = fmaxf(mx, __shfl_xor(mx, 32, 64));
            if (q == 0) wred[0][g][h * 64 + nt * 16 + col] = mx;
        }
        __syncthreads();
        #pragma unroll
        for (int nt = 0; nt < 4; ++nt) {
            int n = h * 64 + nt * 16 + col;
            float gm = fmaxf(fmaxf(wred[0][0][n], wred[0][1][n]),
                             fmaxf(wred[0][2][n], wred[0][3][n]));
            float s = 0.f;
            #pragma unroll
            for (int r = 0; r < 4; ++r) {
                float e = __expf(acc1[nt][r] - gm);
                acc1[nt][r] = e;
                s += e;
            }
            s += __shfl_xor(s, 16, 64);
            s += __shfl_xor(s, 32, 64);
            if (q == 0) wred[1][g][n] = s;
        }
        __syncthreads();
        float inv_[4];
        #pragma unroll
        for (int nt = 0; nt < 4; ++nt) {
            int n = h * 64 + nt * 16 + col;
            float ts = (wred[1][0][n] + wred[1][1][n]) + (wred[1][2][n] + wred[1][3][n]);
            inv_[nt] = 1.0f / ts;
        }

        // prefetch next subtile's first chunk under the epilogue + GEMM2
        if (sub < 3) issue(xv[0], sub + 1, 0);

        // ---- write S (f32, coalesced) + slds (bf16, swizzled) ----
        float* Sp = S + (size_t)(b * M_ + g * 16 + q * 4) * N_ + nq * 512 + sub * 128;
        #pragma unroll
        for (int nt = 0; nt < 4; ++nt) {
            int n = h * 64 + nt * 16 + col;
            #pragma unroll
            for (int r = 0; r < 4; ++r) {
                float p = acc1[nt][r] * inv_[nt];
                Sp[(size_t)r * N_ + n] = p;
                int m = g * 16 + q * 4 + r;
                *(unsigned short*)((char*)uu.slds + m * 256 + ((2 * n) ^ ((m & 7) << 4))) = f2bf(p);
            }
        }
        __syncthreads();

        // ---- pooling GEMM: acc2[c][m] += sum_n xcn[c][n] * slds[m][n] ----
        #pragma unroll
        for (int ks = 0; ks < 4; ++ks) {
            short8 a2[3], bsf[4];
            #pragma unroll
            for (int ci = 0; ci < 3; ++ci) {
                int c = w * 48 + ci * 16 + col;
                a2[ci] = *(const short8*)((char*)xcn + c * 256 +
                                          ((ks * 64 + q * 16) ^ ((c & 7) << 4)));
            }
            #pragma unroll
            for (int mt = 0; mt < 4; ++mt) {
                int m = mt * 16 + col;
                bsf[mt] = *(const short8*)((char*)uu.slds + m * 256 +
                                           ((ks * 64 + q * 16) ^ ((m & 7) << 4)));
            }
            #pragma unroll
            for (int ci = 0; ci < 3; ++ci)
                #pragma unroll
                for (int mt = 0; mt < 4; ++mt)
                    acc2[ci][mt] = __builtin_amdgcn_mfma_f32_16x16x32_bf16(
                        a2[ci], bsf[mt], acc2[ci][mt], 0, 0, 0);
        }
        __syncthreads();
    }

    // ---- epilogue: one atomicAdd pass (6.3M atomics total, as before) ----
    float* Tb = T + (size_t)b * C_ * M_;
    #pragma unroll
    for (int ci = 0; ci < 3; ++ci) {
        int c = w * 48 + ci * 16 + q * 4;
        #pragma unroll
        for (int mt = 0; mt < 4; ++mt)
            #pragma unroll
            for (int r = 0; r < 4; ++r)
                atomicAdd(&Tb[(size_t)(c + r) * M_ + mt * 16 + col], acc2[ci][mt][r]);
    }
}

extern "C" void kernel_launch(void* const* d_in, const int* in_sizes, int n_in,
                              void* d_out, int out_size, void* d_ws, size_t ws_size,
                              hipStream_t stream) {
    const float* x  = (const float*)d_in[0];
    const float* Vw = (const float*)d_in[1];
    const float* Vb = (const float*)d_in[2];
    const float* U  = (const float*)d_in[3];
    float* T = (float*)d_out;                               // [B,C,M]
    float* S = (float*)d_out + (size_t)B_ * C_ * M_;        // [B,M,N]

    unsigned short* W2 = (unsigned short*)d_ws;             // [64][384] bf16
    float* b2 = (float*)((char*)d_ws + 64 * 384 * 2);       // [64] f32

    hipMemsetAsync(T, 0, (size_t)B_ * C_ * M_ * sizeof(float), stream);
    k_w2<<<dim3(8), dim3(256), 0, stream>>>(Vw, Vb, U, W2, b2);
    k_fused<<<dim3(256), dim3(512), 0, stream>>>(x, W2, b2, S, T);
}

// Round 2
// 310.503 us; speedup vs baseline: 1.0865x; 1.0257x over previous
//
#include <hip/hip_runtime.h>
#include <hip/hip_bf16.h>

#define B_ 32
#define C_ 384
#define N_ 4096
#define M_ 64
#define R_ 16

typedef __attribute__((ext_vector_type(8))) short short8;
typedef __attribute__((ext_vector_type(4))) float f32x4;
typedef __attribute__((ext_vector_type(4))) int i32x4;

static __device__ __forceinline__ unsigned short f2bf(float f) {
    union { float f; unsigned u; } v; v.f = f;
    unsigned r = v.u + 0x7fffu + ((v.u >> 16) & 1u);   // RNE
    return (unsigned short)(r >> 16);
}

// =====================================================================
// Kernel 0 (unchanged): W2 = U*Vw (bf16 [64][384]) and b2 = U*Vb -> d_ws.
// =====================================================================
__global__ __launch_bounds__(256) void k_w2(
    const float* __restrict__ Vw, const float* __restrict__ Vb,
    const float* __restrict__ U, unsigned short* __restrict__ W2,
    float* __restrict__ b2)
{
    __shared__ float vws[16 * 384];
    __shared__ float vbs[16];
    const int t = threadIdx.x;

    #pragma unroll
    for (int j = 0; j < 6; ++j)
        ((float4*)vws)[t + j * 256] = ((const float4*)Vw)[t + j * 256];
    if (t < 16) vbs[t] = Vb[t];
    __syncthreads();

    const int m  = blockIdx.x * 8 + (t >> 5);
    const int cg = t & 31;
    float u[R_];
    #pragma unroll
    for (int r = 0; r < R_; ++r) u[r] = U[m * R_ + r];
    if (cg == 0) {
        float a = 0.f;
        #pragma unroll
        for (int r = 0; r < R_; ++r) a = fmaf(u[r], vbs[r], a);
        b2[m] = a;
    }
    #pragma unroll
    for (int j = 0; j < 6; ++j) {
        const int c = cg * 2 + j * 64;
        float a0 = 0.f, a1 = 0.f;
        #pragma unroll
        for (int r = 0; r < R_; ++r) {
            float2 vv = *(const float2*)(vws + r * C_ + c);
            a0 = fmaf(u[r], vv.x, a0);
            a1 = fmaf(u[r], vv.y, a1);
        }
        unsigned pk = (unsigned)f2bf(a0) | ((unsigned)f2bf(a1) << 16);
        *(unsigned*)&W2[m * C_ + c] = pk;
    }
}

// =====================================================================
// Fused kernel, pipelined rev2:
//  - xts double-buffered -> ONE barrier per 64-c chunk (was two)
//  - 3-buffer register prefetch: chunk issued at iter kc is consumed at
//    kc+2; next-subtile chunks 0..2 issued at kc=3,4,5 and fly across
//    softmax+GEMM2 (long phases) -> HBM latency fully hidden
//  - one-pass softmax exchange (max+sum in a single barrier round)
// Grid 32*8 = 256 blocks (1/CU), 512 thr (8 waves).
// LDS: xcn 96K + xts 2x17K + slds 16K + wred 4K = 150 KB.
// =====================================================================
__global__ __launch_bounds__(512, 2) void k_fused(
    const float* __restrict__ x, const unsigned short* __restrict__ W2,
    const float* __restrict__ b2g, float* __restrict__ S, float* __restrict__ T)
{
    __shared__ unsigned short xcn[C_ * 128];      // [c][128n] bf16, XOR-swizzled
    __shared__ unsigned short xts[2][128][68];    // [n][64c] bf16 (+4 pad), dbuf
    __shared__ unsigned short slds[M_ * 128];     // [m][128n] bf16, XOR-swizzled
    __shared__ float wred[2][4][128];             // cross-wave softmax max/sum

    const int t    = threadIdx.x;
    const int lane = t & 63;
    const int col  = lane & 15;
    const int q    = lane >> 4;
    const int w    = t >> 6;
    const int g    = w >> 1;      // logits m-group (16 m each)
    const int h    = w & 1;       // logits n-half (64 n each)

    const int b  = blockIdx.x >> 3;
    const int nq = blockIdx.x & 7;

    // Per-wave W2 A-fragments in VGPRs (48 regs), loaded once (L2-hot).
    short8 af1[12];
    #pragma unroll
    for (int kk = 0; kk < 12; ++kk)
        af1[kk] = *(const short8*)(W2 + (g * 16 + col) * C_ + kk * 32 + q * 8);

    float bias[4];
    #pragma unroll
    for (int r = 0; r < 4; ++r) bias[r] = b2g[g * 16 + q * 4 + r];

    // Pooling accumulators: c = w*48 + ci*16 + (q*4+r), m = mt*16 + col.
    f32x4 acc2[3][4];
    #pragma unroll
    for (int ci = 0; ci < 3; ++ci)
        #pragma unroll
        for (int mt = 0; mt < 4; ++mt) acc2[ci][mt] = (f32x4){0.f, 0.f, 0.f, 0.f};

    const float* xb = x + (size_t)b * C_ * N_ + nq * 512 + 2 * lane;

    float2 xv[3][8];                // 3-deep chunk prefetch ring (48 VGPRs)

    auto ISSUE = [&](float2 (&dst)[8], int subp, int kcp) {
        const float* xp = xb + (size_t)(kcp * 64 + w * 8) * N_ + subp * 128;
        #pragma unroll
        for (int i = 0; i < 8; ++i)
            dst[i] = *(const float2*)(xp + (size_t)i * N_);
    };

    auto CONVERT = [&](float2 (&v)[8], int kcp, int buf) {
        unsigned short bx[8], by[8];
        #pragma unroll
        for (int i = 0; i < 8; ++i) { bx[i] = f2bf(v[i].x); by[i] = f2bf(v[i].y); }
        // xcn[c][n]: all lanes same row -> conflict-free b32 writes
        #pragma unroll
        for (int i = 0; i < 8; ++i) {
            int c = kcp * 64 + w * 8 + i;
            unsigned pk = (unsigned)bx[i] | ((unsigned)by[i] << 16);
            *(unsigned*)((char*)xcn + c * 256 + ((lane * 4) ^ ((c & 7) << 4))) = pk;
        }
        // xts[buf][n][c]: b128 rows 2*lane / 2*lane+1 (pad 68 -> bank-floor)
        i32x4 pa, pb;
        #pragma unroll
        for (int j = 0; j < 4; ++j) {
            pa[j] = (int)((unsigned)bx[2 * j] | ((unsigned)bx[2 * j + 1] << 16));
            pb[j] = (int)((unsigned)by[2 * j] | ((unsigned)by[2 * j + 1] << 16));
        }
        *(i32x4*)&xts[buf][2 * lane][w * 8]     = pa;
        *(i32x4*)&xts[buf][2 * lane + 1][w * 8] = pb;
    };

    ISSUE(xv[0], 0, 0);
    ISSUE(xv[1], 0, 1);
    ISSUE(xv[2], 0, 2);

    for (int sub = 0; sub < 4; ++sub) {
        f32x4 acc1[4];
        #pragma unroll
        for (int nt = 0; nt < 4; ++nt) acc1[nt] = (f32x4){0.f, 0.f, 0.f, 0.f};

        // prologue: chunk 0 (loads issued long ago) -> xts[0] + xcn slab 0
        CONVERT(xv[0], 0, 0);
        __syncthreads();

        #pragma unroll
        for (int kc = 0; kc < 6; ++kc) {
            // stage chunk kc+1 into the other xts buffer (loads 2 iters old)
            if (kc < 5) CONVERT(xv[(kc + 1) % 3], kc + 1, (kc + 1) & 1);
            // refill ring: local chunks 3..5, then next-subtile chunks 0..2
            if (kc < 3)          ISSUE(xv[kc % 3], sub, kc + 3);
            else if (sub < 3)    ISSUE(xv[kc % 3], sub + 1, kc - 3);

            // GEMM1 on xts[kc&1]
            #pragma unroll
            for (int ks = 0; ks < 2; ++ks) {
                short8 bfr[4];
                #pragma unroll
                for (int nt = 0; nt < 4; ++nt)
                    bfr[nt] = *(const short8*)&xts[kc & 1][h * 64 + nt * 16 + col][ks * 32 + q * 8];
                #pragma unroll
                for (int nt = 0; nt < 4; ++nt)
                    acc1[nt] = __builtin_amdgcn_mfma_f32_16x16x32_bf16(
                        af1[kc * 2 + ks], bfr[nt], acc1[nt], 0, 0, 0);
            }
            __syncthreads();   // xts[(kc+1)&1] published; xts[kc&1] reads done
        }

        // ---- one-pass softmax exchange over m = 64 ----
        float mxl[4];
        #pragma unroll
        for (int nt = 0; nt < 4; ++nt) {
            float mx = -3.4e38f;
            #pragma unroll
            for (int r = 0; r < 4; ++r) {
                float vv = acc1[nt][r] + bias[r];
                acc1[nt][r] = vv;
                mx = fmaxf(mx, vv);
            }
            mx = fmaxf(mx, __shfl_xor(mx, 16, 64));
            mx = fmaxf(mx, __shfl_xor(mx, 32, 64));
            float s = 0.f;
            #pragma unroll
            for (int r = 0; r < 4; ++r) {
                float e = __expf(acc1[nt][r] - mx);
                acc1[nt][r] = e;
                s += e;
            }
            s += __shfl_xor(s, 16, 64);
            s += __shfl_xor(s, 32, 64);
            mxl[nt] = mx;
            if (q == 0) {
                int n = h * 64 + nt * 16 + col;
                wred[0][g][n] = mx;
                wred[1][g][n] = s;
            }
        }
        __syncthreads();

        float scl[4];
        #pragma unroll
        for (int nt = 0; nt < 4; ++nt) {
            int n = h * 64 + nt * 16 + col;
            float m0 = wred[0][0][n], m1 = wred[0][1][n];
            float m2 = wred[0][2][n], m3 = wred[0][3][n];
            float M  = fmaxf(fmaxf(m0, m1), fmaxf(m2, m3));
            float tot = wred[1][0][n] * __expf(m0 - M) + wred[1][1][n] * __expf(m1 - M)
                      + wred[1][2][n] * __expf(m2 - M) + wred[1][3][n] * __expf(m3 - M);
            scl[nt] = __expf(mxl[nt] - M) / tot;
        }

        // ---- write S (f32) + slds (bf16, swizzled) ----
        float* Sp = S + (size_t)(b * M_ + g * 16 + q * 4) * N_ + nq * 512 + sub * 128;
        #pragma unroll
        for (int nt = 0; nt < 4; ++nt) {
            int n = h * 64 + nt * 16 + col;
            #pragma unroll
            for (int r = 0; r < 4; ++r) {
                float p = acc1[nt][r] * scl[nt];
                Sp[(size_t)r * N_ + n] = p;
                int m = g * 16 + q * 4 + r;
                *(unsigned short*)((char*)slds + m * 256 + ((2 * n) ^ ((m & 7) << 4))) = f2bf(p);
            }
        }
        __syncthreads();

        // ---- pooling GEMM: acc2[c][m] += sum_n xcn[c][n] * slds[m][n] ----
        #pragma unroll
        for (int ks = 0; ks < 4; ++ks) {
            short8 a2[3], bsf[4];
            #pragma unroll
            for (int ci = 0; ci < 3; ++ci) {
                int c = w * 48 + ci * 16 + col;
                a2[ci] = *(const short8*)((char*)xcn + c * 256 +
                                          ((ks * 64 + q * 16) ^ ((c & 7) << 4)));
            }
            #pragma unroll
            for (int mt = 0; mt < 4; ++mt) {
                int m = mt * 16 + col;
                bsf[mt] = *(const short8*)((char*)slds + m * 256 +
                                           ((ks * 64 + q * 16) ^ ((m & 7) << 4)));
            }
            #pragma unroll
            for (int ci = 0; ci < 3; ++ci)
                #pragma unroll
                for (int mt = 0; mt < 4; ++mt)
                    acc2[ci][mt] = __builtin_amdgcn_mfma_f32_16x16x32_bf16(
                        a2[ci], bsf[mt], acc2[ci][mt], 0, 0, 0);
        }
        __syncthreads();   // xcn/slds reads done before next subtile overwrites
    }

    // ---- epilogue: one atomicAdd pass ----
    float* Tb = T + (size_t)b * C_ * M_;
    #pragma unroll
    for (int ci = 0; ci < 3; ++ci) {
        int c = w * 48 + ci * 16 + q * 4;
        #pragma unroll
        for (int mt = 0; mt < 4; ++mt)
            #pragma unroll
            for (int r = 0; r < 4; ++r)
                atomicAdd(&Tb[(size_t)(c + r) * M_ + mt * 16 + col], acc2[ci][mt][r]);
    }
}

extern "C" void kernel_launch(void* const* d_in, const int* in_sizes, int n_in,
                              void* d_out, int out_size, void* d_ws, size_t ws_size,
                              hipStream_t stream) {
    const float* x  = (const float*)d_in[0];
    const float* Vw = (const float*)d_in[1];
    const float* Vb = (const float*)d_in[2];
    const float* U  = (const float*)d_in[3];
    float* T = (float*)d_out;                               // [B,C,M]
    float* S = (float*)d_out + (size_t)B_ * C_ * M_;        // [B,M,N]

    unsigned short* W2 = (unsigned short*)d_ws;             // [64][384] bf16
    float* b2 = (float*)((char*)d_ws + 64 * 384 * 2);       // [64] f32

    hipMemsetAsync(T, 0, (size_t)B_ * C_ * M_ * sizeof(float), stream);
    k_w2<<<dim3(8), dim3(256), 0, stream>>>(Vw, Vb, U, W2, b2);
    k_fused<<<dim3(256), dim3(512), 0, stream>>>(x, W2, b2, S, T);
}